// Round 1
// baseline (2481.632 us; speedup 1.0000x reference)
//
#include <hip/hip_runtime.h>

#define NPTS 1000000
#define CH 128
#define NG 100000

// 32 threads per point; each thread handles 4 consecutive channels.
__global__ void accum_kernel(const float* __restrict__ feat,
                             const int* __restrict__ gid,
                             float* __restrict__ sums,
                             float* __restrict__ counts) {
    long long t = (long long)blockIdx.x * blockDim.x + threadIdx.x;
    int point = (int)(t >> 5);
    int sub = (int)(t & 31);
    if (point >= NPTS) return;
    int g = gid[point];
    const float4 v = ((const float4*)(feat + (long long)point * CH))[sub];
    float* dst = sums + (long long)g * CH + sub * 4;
    atomicAdd(dst + 0, v.x);
    atomicAdd(dst + 1, v.y);
    atomicAdd(dst + 2, v.z);
    atomicAdd(dst + 3, v.w);
    if (sub == 0) atomicAdd(counts + g, 1.0f);
}

__global__ void inv_kernel(float* __restrict__ counts) {
    int g = blockIdx.x * blockDim.x + threadIdx.x;
    if (g < NG) counts[g] = 1.0f / fmaxf(counts[g], 1.0f);
}

// 32 threads per point; coalesced float4 gather/store.
__global__ void gather_kernel(const float* __restrict__ sums,
                              const float* __restrict__ inv,
                              const int* __restrict__ gid,
                              float* __restrict__ out) {
    long long t = (long long)blockIdx.x * blockDim.x + threadIdx.x;
    int point = (int)(t >> 5);
    int sub = (int)(t & 31);
    if (point >= NPTS) return;
    int g = gid[point];
    float ic = inv[g];
    float4 v = ((const float4*)(sums + (long long)g * CH))[sub];
    v.x *= ic; v.y *= ic; v.z *= ic; v.w *= ic;
    ((float4*)(out + (long long)point * CH))[sub] = v;
}

extern "C" void kernel_launch(void* const* d_in, const int* in_sizes, int n_in,
                              void* d_out, int out_size, void* d_ws, size_t ws_size,
                              hipStream_t stream) {
    const float* feat = (const float*)d_in[1];
    const int* gid = (const int*)d_in[2];
    float* out = (float*)d_out;

    float* sums = (float*)d_ws;                 // NG * CH floats
    float* counts = sums + (long long)NG * CH;  // NG floats

    size_t zero_bytes = ((size_t)NG * CH + NG) * sizeof(float);
    hipMemsetAsync(d_ws, 0, zero_bytes, stream);

    const int block = 256;
    long long total = (long long)NPTS * 32;
    int grid = (int)((total + block - 1) / block);

    accum_kernel<<<grid, block, 0, stream>>>(feat, gid, sums, counts);
    inv_kernel<<<(NG + block - 1) / block, block, 0, stream>>>(counts);
    gather_kernel<<<grid, block, 0, stream>>>(sums, counts, gid, out);
}